// Round 11
// baseline (427.820 us; speedup 1.0000x reference)
//
#include <hip/hip_runtime.h>
#include <hip/hip_bf16.h>

#define H 256
#define KNN 16
#define NPT 256
#define BB 64

typedef unsigned short u16;
typedef unsigned int u32;
typedef __attribute__((ext_vector_type(8))) short shortx8;
typedef __attribute__((ext_vector_type(4))) float floatx4;

// RNE f32->bf16 via hw cvt; same rounding as manual (u + 0x7fff + lsb) >> 16.
__device__ __forceinline__ u16 f2b(float f) {
    return __builtin_bit_cast(u16, __float2bfloat16(f));
}
__device__ __forceinline__ float b2f(u16 u) {
    return __uint_as_float(((u32)u) << 16);
}

// tanh via hw exp2: 1 - 2/(exp2(x*2log2e)+1). |err| ~1e-6, saturates correctly.
__device__ __forceinline__ float fast_tanh(float x) {
    float e = __builtin_amdgcn_exp2f(x * 2.88539008177793f);
    return 1.0f - 2.0f * __builtin_amdgcn_rcpf(e + 1.0f);
}

// ---------------------------------------------------------------------------
// K0: prep — bf16 transposed weights [n][k] for MFMA B-fragments, plus
// featB (bf16 copy of feat). Blocks [0,1184): weights; [1184,5280): featB.
// w1t is 256x32: K padded 4->32, k=4 holds b1 (bias lane), k>4 zero.
// NOTE: keep prep/knn/gate SEPARATE dispatches in front of the MFMA kernels —
// R9 showed that restructuring the front pushes the harness's poison-
// writeback drain into edge_mfma's window (WRITE_SIZE 8->136 MiB, edge
// +42 us) with zero front-time gain.
// ---------------------------------------------------------------------------
__global__ __launch_bounds__(256) void prep_kernel(
    const float* __restrict__ feat,
    const float* __restrict__ w2, const float* __restrict__ we1,
    const float* __restrict__ wm, const float* __restrict__ wo,
    const float* __restrict__ w1, const float* __restrict__ b1,
    u16* __restrict__ w2t, u16* __restrict__ we1t,
    u16* __restrict__ wmt, u16* __restrict__ wot, u16* __restrict__ w1t,
    u16* __restrict__ featB) {
    int blk = blockIdx.x;
    if (blk < 1184) {
        int tid = blk * 256 + threadIdx.x;
        if (tid < 65536) {                       // w2t: 256 x 256
            int n = tid >> 8, k = tid & 255;
            w2t[tid] = f2b(w2[k * 256 + n]);
        } else if (tid < 98304) {                // we1t: 128 x 256
            int t = tid - 65536;
            int n = t >> 8, k = t & 255;
            we1t[t] = f2b(we1[k * 128 + n]);
        } else if (tid < 163840) {               // wmt: 256 x 256
            int t = tid - 98304;
            int n = t >> 8, k = t & 255;
            wmt[t] = f2b(wm[k * 256 + n]);
        } else if (tid < 294912) {               // wot: 256 x 512
            int t = tid - 163840;
            int n = t >> 9, k = t & 511;
            wot[t] = f2b(wo[k * 256 + n]);
        } else {                                 // w1t: 256 x 32
            int t = tid - 294912;
            int n = t >> 5, k = t & 31;
            float v = (k < 4) ? w1[k * 256 + n] : (k == 4 ? b1[n] : 0.0f);
            w1t[t] = f2b(v);
        }
        return;
    }
    // featB: 4 elements per thread, 4096 blocks x 256 threads x 4 = 4.19M
    int e = (blk - 1184) * 256 + threadIdx.x;
    float4 f = *(const float4*)&feat[(size_t)e * 4];
    uint2 st;
    st.x = (u32)f2b(f.x) | ((u32)f2b(f.y) << 16);
    st.y = (u32)f2b(f.z) | ((u32)f2b(f.w) << 16);
    *(uint2*)&featB[(size_t)e * 4] = st;
}

// ---------------------------------------------------------------------------
// K1: exact KNN k=16, stable (d, idx)-lexicographic == jax.lax.top_k(-dist).
// 256 blocks: block = (batch, quarter of points). 4 scanner-waves per point
// group; wave s scans m in [s*64, s*64+64); wave 0 merges.
// ---------------------------------------------------------------------------
__global__ __launch_bounds__(256) void knn_kernel(const float* __restrict__ centers,
                                                  int* __restrict__ knn) {
    __shared__ float cx[NPT], cy[NPT], cz[NPT], sq[NPT];
    __shared__ float dl[4][64][17];
    __shared__ int il[4][64][17];
    int blk = blockIdx.x;
    int b = blk >> 2, n0 = (blk & 3) * 64;
    int h = threadIdx.x;
    int s = h >> 6, pt = h & 63;
    {
        const float* cb = centers + (size_t)b * NPT * 3;
        float x = cb[h * 3 + 0], y = cb[h * 3 + 1], z = cb[h * 3 + 2];
        cx[h] = x; cy[h] = y; cz[h] = z;
        sq[h] = x * x + y * y + z * z;
    }
    __syncthreads();
    int n = n0 + pt;
    float x = cx[n], y = cy[n], z = cz[n], sn = sq[n];
    float bd[KNN];
    int bi[KNN];
#pragma unroll
    for (int j = 0; j < KNN; j++) { bd[j] = 1e30f; bi[j] = 0x7fffffff; }
    for (int mm = 0; mm < 64; mm++) {
        int m = s * 64 + mm;
        float dot = x * cx[m] + y * cy[m] + z * cz[m];
        float d2 = (sn + sq[m]) - 2.0f * dot;
        float d = sqrtf(fmaxf(d2, 0.0f));
        if (d < bd[KNN - 1]) {  // in-order scan + strict < == lexicographic
            bd[KNN - 1] = d; bi[KNN - 1] = m;
#pragma unroll
            for (int p = KNN - 1; p > 0; --p) {
                if (bd[p - 1] > bd[p]) {
                    float td = bd[p - 1]; bd[p - 1] = bd[p]; bd[p] = td;
                    int ti = bi[p - 1]; bi[p - 1] = bi[p]; bi[p] = ti;
                }
            }
        }
    }
#pragma unroll
    for (int j = 0; j < KNN; j++) { dl[s][pt][j] = bd[j]; il[s][pt][j] = bi[j]; }
    __syncthreads();
    if (s == 0) {
        float md[KNN];
        int mi[KNN];
#pragma unroll
        for (int j = 0; j < KNN; j++) { md[j] = dl[0][pt][j]; mi[j] = il[0][pt][j]; }
        for (int t = 1; t < 4; t++) {
            for (int j = 0; j < KNN; j++) {
                float d = dl[t][pt][j];
                int idx = il[t][pt][j];
                bool ins = (d < md[KNN - 1]) || (d == md[KNN - 1] && idx < mi[KNN - 1]);
                if (!ins) break;  // source list sorted lexicographically
                md[KNN - 1] = d; mi[KNN - 1] = idx;
#pragma unroll
                for (int p = KNN - 1; p > 0; --p) {
                    bool sw = (md[p - 1] > md[p]) ||
                              (md[p - 1] == md[p] && mi[p - 1] > mi[p]);
                    if (sw) {
                        float td = md[p - 1]; md[p - 1] = md[p]; md[p] = td;
                        int ti = mi[p - 1]; mi[p - 1] = mi[p]; mi[p] = ti;
                    }
                }
            }
        }
        int* kp = knn + (b * NPT + n0 + pt) * KNN;
#pragma unroll
        for (int j = 0; j < KNN; j++) kp[j] = mi[j];
    }
}

// ---------------------------------------------------------------------------
// K2: text gate / bias per batch. 512 threads: 0..255 gate, 256..511 tbias.
// ---------------------------------------------------------------------------
__global__ __launch_bounds__(512) void gate_kernel(const float* __restrict__ tg_g,
                                                   const float* __restrict__ wg,
                                                   const float* __restrict__ bg,
                                                   const float* __restrict__ wtb,
                                                   const float* __restrict__ btb,
                                                   float* __restrict__ gate,
                                                   float* __restrict__ tbias) {
    __shared__ float tg[H];
    int b = blockIdx.x, t = threadIdx.x;
    if (t < H) tg[t] = tg_g[b * H + t];
    __syncthreads();
    int h = t & 255;
    if (t < H) {
        float ag = bg[h];
#pragma unroll 4
        for (int i = 0; i < H; i++) ag += tg[i] * wg[i * H + h];
        gate[b * H + h] = 1.0f / (1.0f + expf(-ag));
    } else {
        float ab = btb[h];
#pragma unroll 4
        for (int i = 0; i < H; i++) ab += tg[i] * wtb[i * H + h];
        tbias[b * H + h] = ab;
    }
}

// ---------------------------------------------------------------------------
// K3: MSGB = bf16(relu(feat @ Wm + bm)), MFMA, 64 points/block.
// ---------------------------------------------------------------------------
__global__ __launch_bounds__(256, 4) void msg_mfma(const u16* __restrict__ featB,
                                                   const u16* __restrict__ wmt,
                                                   const float* __restrict__ bm,
                                                   u16* __restrict__ MSGB) {
    __shared__ __attribute__((aligned(16))) u16 A[64][264];
    int p0 = blockIdx.x * 64, h = threadIdx.x;
    int w = h >> 6, lane = h & 63, quad = lane >> 4, lq = lane & 15;
#pragma unroll 8
    for (int row = 0; row < 64; row++)
        A[row][h] = featB[(size_t)(p0 + row) * H + h];
    __syncthreads();
    floatx4 acc[4][4];
#pragma unroll
    for (int rt = 0; rt < 4; rt++)
#pragma unroll
        for (int ct = 0; ct < 4; ct++) acc[rt][ct] = (floatx4){0, 0, 0, 0};
#pragma unroll 2
    for (int kt = 0; kt < 8; kt++) {
        shortx8 bf[4];
#pragma unroll
        for (int ct = 0; ct < 4; ct++)
            bf[ct] = *(const shortx8*)&wmt[(w * 64 + ct * 16 + lq) * 256 + kt * 32 + quad * 8];
#pragma unroll
        for (int rt = 0; rt < 4; rt++) {
            shortx8 a = *(const shortx8*)&A[rt * 16 + lq][kt * 32 + quad * 8];
#pragma unroll
            for (int ct = 0; ct < 4; ct++)
                acc[rt][ct] = __builtin_amdgcn_mfma_f32_16x16x32_bf16(a, bf[ct], acc[rt][ct], 0, 0, 0);
        }
    }
#pragma unroll
    for (int ct = 0; ct < 4; ct++) {
        int col = w * 64 + ct * 16 + lq;
        float bmc = bm[col];
#pragma unroll
        for (int rt = 0; rt < 4; rt++)
#pragma unroll
            for (int r = 0; r < 4; r++) {
                int row = rt * 16 + quad * 4 + r;
                MSGB[(size_t)(p0 + row) * H + col] = f2b(fmaxf(acc[rt][ct][r] + bmc, 0.0f));
            }
    }
}

// ---------------------------------------------------------------------------
// K4: fused edge pipeline, 4 points/block (M=64 edges). g1 via MFMA with
// bias folded into K-slot 4. fb/MSG gathers + ctx write in bf16.
// NEW (R11): fb gather (64 scattered loads) register-prefetched right after
// the nidx barrier so the L2 latency overlaps phase2+GEMM1 (~4000 cyc) —
// previously issued inside epilogue1 where each load stalled its tanh chain.
// VGPR 60 -> ~124, still 4 waves/SIMD (limit 128 at 4 blocks/CU).
// ---------------------------------------------------------------------------
__global__ __launch_bounds__(256, 4) void edge_mfma(
    const float* __restrict__ feat, const u16* __restrict__ featB,
    const float* __restrict__ centers,
    const u16* __restrict__ w1t,
    const u16* __restrict__ w2t, const float* __restrict__ b2v,
    const u16* __restrict__ we1t, const float* __restrict__ be1,
    const float* __restrict__ we2, const float* __restrict__ be2,
    const int* __restrict__ knn, const float* __restrict__ gateG,
    const float* __restrict__ tbiasG, const u16* __restrict__ MSGB,
    u16* __restrict__ ctxB) {
    __shared__ __attribute__((aligned(16))) u16 A[64][264];  // g1 then edge_feat
    __shared__ float fnS[4][H];
    __shared__ __attribute__((aligned(16))) float geomS[64][4];
    __shared__ int nidxS[64];
    __shared__ float part[4][64];
    __shared__ float logitsS[64];
    __shared__ float alphaS[64];

    int bn0 = blockIdx.x * 4;
    int b = bn0 >> 8, n0 = bn0 & 255;
    int h = threadIdx.x;
    int w = h >> 6, lane = h & 63, quad = lane >> 4, lq = lane & 15;

    // phase 0: nidx + fn staging
    if (h < 64) nidxS[h] = knn[bn0 * KNN + h];
#pragma unroll
    for (int p = 0; p < 4; p++)
        fnS[p][h] = feat[(size_t)(bn0 + p) * H + h];
    // phase 1: geom per edge-row (h<64: point p=h>>4, neighbor j=h&15);
    // reads only own-thread nidxS[h] write from phase 0.
    if (h < 64) {
        int p = h >> 4;
        int m = nidxS[h];
        int n = n0 + p;
        const float* cb = centers + (size_t)b * NPT * 3;
        float rx = cb[m * 3 + 0] - cb[n * 3 + 0];
        float ry = cb[m * 3 + 1] - cb[n * 3 + 1];
        float rz = cb[m * 3 + 2] - cb[n * 3 + 2];
        float dist = sqrtf(rx * rx + ry * ry + rz * rz) + 1e-6f;
        geomS[h][0] = rx; geomS[h][1] = ry; geomS[h][2] = rz;
        geomS[h][3] = log1pf(dist);
    }
    __syncthreads();

    // fb register prefetch: all epilogue-1 neighbor-feat values, issued here
    // so their latency hides under phase2 + GEMM1.
    float fbp[4][4][4];  // [ct][rt][r]
#pragma unroll
    for (int ct = 0; ct < 4; ct++) {
        int col = w * 64 + ct * 16 + lq;
#pragma unroll
        for (int rt = 0; rt < 4; rt++)
#pragma unroll
            for (int r = 0; r < 4; r++)
                fbp[ct][rt][r] =
                    b2f(featB[((size_t)b * NPT + nidxS[rt * 16 + quad * 4 + r]) * H + col]);
    }

    // phase 2: g1[64][256] = relu(geomP @ W1t) via MFMA (K=32 padded, k=4 bias)
    {
        shortx8 bw1[4];
#pragma unroll
        for (int ct = 0; ct < 4; ct++)
            bw1[ct] = *(const shortx8*)&w1t[(w * 64 + ct * 16 + lq) * 32 + quad * 8];
#pragma unroll
        for (int rt = 0; rt < 4; rt++) {
            shortx8 ag = {0, 0, 0, 0, 0, 0, 0, 0};
            if (quad == 0) {
                float4 g = *(const float4*)&geomS[rt * 16 + lq][0];
                ag[0] = (short)f2b(g.x);
                ag[1] = (short)f2b(g.y);
                ag[2] = (short)f2b(g.z);
                ag[3] = (short)f2b(g.w);
                ag[4] = (short)0x3F80;  // 1.0 -> multiplies bias row of w1t
            }
#pragma unroll
            for (int ct = 0; ct < 4; ct++) {
                floatx4 accg = __builtin_amdgcn_mfma_f32_16x16x32_bf16(
                    ag, bw1[ct], (floatx4){0, 0, 0, 0}, 0, 0, 0);
#pragma unroll
                for (int r = 0; r < 4; r++)
                    A[rt * 16 + quad * 4 + r][w * 64 + ct * 16 + lq] =
                        f2b(fmaxf(accg[r], 0.0f));
            }
        }
    }
    __syncthreads();

    // GEMM1: C1[64][256] = g1 @ W2
    floatx4 acc[4][4];
#pragma unroll
    for (int rt = 0; rt < 4; rt++)
#pragma unroll
        for (int ct = 0; ct < 4; ct++) acc[rt][ct] = (floatx4){0, 0, 0, 0};
#pragma unroll 2
    for (int kt = 0; kt < 8; kt++) {
        shortx8 bf[4];
#pragma unroll
        for (int ct = 0; ct < 4; ct++)
            bf[ct] = *(const shortx8*)&w2t[(w * 64 + ct * 16 + lq) * 256 + kt * 32 + quad * 8];
#pragma unroll
        for (int rt = 0; rt < 4; rt++) {
            shortx8 a = *(const shortx8*)&A[rt * 16 + lq][kt * 32 + quad * 8];
#pragma unroll
            for (int ct = 0; ct < 4; ct++)
                acc[rt][ct] = __builtin_amdgcn_mfma_f32_16x16x32_bf16(a, bf[ct], acc[rt][ct], 0, 0, 0);
        }
    }
    __syncthreads();  // all g1 reads done

    // epilogue1: edge_feat = tanh(fn + fnb + relu(C1+b2)*gate + tbias) -> A
#pragma unroll
    for (int ct = 0; ct < 4; ct++) {
        int col = w * 64 + ct * 16 + lq;
        float b2c = b2v[col];
        float gc = gateG[b * H + col];
        float tc = tbiasG[b * H + col];
#pragma unroll
        for (int rt = 0; rt < 4; rt++) {
            float fnc = fnS[rt][col];
#pragma unroll
            for (int r = 0; r < 4; r++) {
                int row = rt * 16 + quad * 4 + r;
                float emb = fmaxf(acc[rt][ct][r] + b2c, 0.0f);
                float ef = fast_tanh(fnc + fbp[ct][rt][r] + emb * gc + tc);
                A[row][col] = f2b(ef);
            }
        }
    }
    __syncthreads();

    // GEMM2: C2[64][128] = edge_feat @ We1
    floatx4 acc2[4][2];
#pragma unroll
    for (int rt = 0; rt < 4; rt++)
#pragma unroll
        for (int c2 = 0; c2 < 2; c2++) acc2[rt][c2] = (floatx4){0, 0, 0, 0};
#pragma unroll 2
    for (int kt = 0; kt < 8; kt++) {
        shortx8 bf[2];
#pragma unroll
        for (int c2 = 0; c2 < 2; c2++)
            bf[c2] = *(const shortx8*)&we1t[(w * 32 + c2 * 16 + lq) * 256 + kt * 32 + quad * 8];
#pragma unroll
        for (int rt = 0; rt < 4; rt++) {
            shortx8 a = *(const shortx8*)&A[rt * 16 + lq][kt * 32 + quad * 8];
#pragma unroll
            for (int c2 = 0; c2 < 2; c2++)
                acc2[rt][c2] = __builtin_amdgcn_mfma_f32_16x16x32_bf16(a, bf[c2], acc2[rt][c2], 0, 0, 0);
        }
    }

    // logits partials
    float pl[4][4];
#pragma unroll
    for (int rt = 0; rt < 4; rt++)
#pragma unroll
        for (int r = 0; r < 4; r++) pl[rt][r] = 0.0f;
#pragma unroll
    for (int c2 = 0; c2 < 2; c2++) {
        int col = w * 32 + c2 * 16 + lq;
        float be1c = be1[col], w2c = we2[col];
#pragma unroll
        for (int rt = 0; rt < 4; rt++)
#pragma unroll
            for (int r = 0; r < 4; r++)
                pl[rt][r] += fmaxf(acc2[rt][c2][r] + be1c, 0.0f) * w2c;
    }
#pragma unroll
    for (int d = 1; d < 16; d <<= 1)
#pragma unroll
        for (int rt = 0; rt < 4; rt++)
#pragma unroll
            for (int r = 0; r < 4; r++) pl[rt][r] += __shfl_xor(pl[rt][r], d, 16);
    if (lq == 0) {
#pragma unroll
        for (int rt = 0; rt < 4; rt++)
#pragma unroll
            for (int r = 0; r < 4; r++)
                part[w][rt * 16 + quad * 4 + r] = pl[rt][r];
    }
    __syncthreads();
    if (h < 64)
        logitsS[h] = part[0][h] + part[1][h] + part[2][h] + part[3][h] + be2[0];
    __syncthreads();
    if (h < 64) {
        int base = (h >> 4) * 16;
        float mx = -1e30f;
#pragma unroll
        for (int j = 0; j < KNN; j++) mx = fmaxf(mx, logitsS[base + j]);
        float sum = 0.0f;
#pragma unroll
        for (int j = 0; j < KNN; j++) sum += expf(logitsS[base + j] - mx);
        alphaS[h] = expf(logitsS[h] - mx) / sum;
    }
    __syncthreads();

    // ctx: thread -> (point p, 4 cols); bf16 gather over 16 nbrs, bf16 write
    {
        int p = h >> 6, cg = (h & 63) * 4;
        float4 c = {0, 0, 0, 0};
#pragma unroll
        for (int j = 0; j < KNN; j++) {
            float al = alphaS[p * 16 + j];
            const u32* mp = (const u32*)&MSGB[((size_t)b * NPT + nidxS[p * 16 + j]) * H + cg];
            u32 m0 = mp[0], m1 = mp[1];
            c.x += al * __uint_as_float(m0 << 16);
            c.y += al * __uint_as_float(m0 & 0xFFFF0000u);
            c.z += al * __uint_as_float(m1 << 16);
            c.w += al * __uint_as_float(m1 & 0xFFFF0000u);
        }
        uint2 st;
        st.x = (u32)f2b(c.x) | ((u32)f2b(c.y) << 16);
        st.y = (u32)f2b(c.z) | ((u32)f2b(c.w) << 16);
        *(uint2*)&ctxB[(size_t)(bn0 + p) * H + cg] = st;
    }
}

// ---------------------------------------------------------------------------
// K5: out = LN(feat + relu([feat|ctx] @ Wo + bo)), MFMA, 32 points/block.
// ---------------------------------------------------------------------------
__global__ __launch_bounds__(256, 4) void out_mfma(const float* __restrict__ feat,
                                                   const u16* __restrict__ featB,
                                                   const u16* __restrict__ ctxB,
                                                   const u16* __restrict__ wot,
                                                   const float* __restrict__ bo,
                                                   const float* __restrict__ gamma,
                                                   const float* __restrict__ beta,
                                                   float* __restrict__ out) {
    __shared__ __attribute__((aligned(16))) u16 A[32][520];
    __shared__ float redS[4][32], redS2[4][32];
    int p0 = blockIdx.x * 32, h = threadIdx.x;
    int w = h >> 6, lane = h & 63, quad = lane >> 4, lq = lane & 15;
#pragma unroll 8
    for (int row = 0; row < 32; row++) {
        A[row][h]       = featB[(size_t)(p0 + row) * H + h];
        A[row][256 + h] = ctxB[(size_t)(p0 + row) * H + h];
    }
    __syncthreads();
    floatx4 acc[2][4];
#pragma unroll
    for (int rt = 0; rt < 2; rt++)
#pragma unroll
        for (int ct = 0; ct < 4; ct++) acc[rt][ct] = (floatx4){0, 0, 0, 0};
#pragma unroll 2
    for (int kt = 0; kt < 16; kt++) {
        shortx8 bf[4];
#pragma unroll
        for (int ct = 0; ct < 4; ct++)
            bf[ct] = *(const shortx8*)&wot[(w * 64 + ct * 16 + lq) * 512 + kt * 32 + quad * 8];
#pragma unroll
        for (int rt = 0; rt < 2; rt++) {
            shortx8 a = *(const shortx8*)&A[rt * 16 + lq][kt * 32 + quad * 8];
#pragma unroll
            for (int ct = 0; ct < 4; ct++)
                acc[rt][ct] = __builtin_amdgcn_mfma_f32_16x16x32_bf16(a, bf[ct], acc[rt][ct], 0, 0, 0);
        }
    }
    float x[2][4][4];
    float sm[2][4], sq2[2][4];
#pragma unroll
    for (int rt = 0; rt < 2; rt++)
#pragma unroll
        for (int r = 0; r < 4; r++) { sm[rt][r] = 0.0f; sq2[rt][r] = 0.0f; }
#pragma unroll
    for (int rt = 0; rt < 2; rt++)
#pragma unroll
        for (int ct = 0; ct < 4; ct++) {
            int col = w * 64 + ct * 16 + lq;
            float boc = bo[col];
#pragma unroll
            for (int r = 0; r < 4; r++) {
                int row = rt * 16 + quad * 4 + r;
                float xx = feat[(size_t)(p0 + row) * H + col] +
                           fmaxf(acc[rt][ct][r] + boc, 0.0f);
                x[rt][ct][r] = xx;
                sm[rt][r] += xx;
                sq2[rt][r] += xx * xx;
            }
        }
#pragma unroll
    for (int d = 1; d < 16; d <<= 1)
#pragma unroll
        for (int rt = 0; rt < 2; rt++)
#pragma unroll
            for (int r = 0; r < 4; r++) {
                sm[rt][r] += __shfl_xor(sm[rt][r], d, 16);
                sq2[rt][r] += __shfl_xor(sq2[rt][r], d, 16);
            }
    if (lq == 0) {
#pragma unroll
        for (int rt = 0; rt < 2; rt++)
#pragma unroll
            for (int r = 0; r < 4; r++) {
                redS[w][rt * 16 + quad * 4 + r] = sm[rt][r];
                redS2[w][rt * 16 + quad * 4 + r] = sq2[rt][r];
            }
    }
    __syncthreads();
#pragma unroll
    for (int rt = 0; rt < 2; rt++)
#pragma unroll
        for (int r = 0; r < 4; r++) {
            int row = rt * 16 + quad * 4 + r;
            float s1 = redS[0][row] + redS[1][row] + redS[2][row] + redS[3][row];
            float s2 = redS2[0][row] + redS2[1][row] + redS2[2][row] + redS2[3][row];
            float mu = s1 * (1.0f / H);
            float var = s2 * (1.0f / H) - mu * mu;
            float inv = rsqrtf(fmaxf(var, 0.0f) + 1e-5f);
#pragma unroll
            for (int ct = 0; ct < 4; ct++) {
                int col = w * 64 + ct * 16 + lq;
                out[(size_t)(p0 + row) * H + col] =
                    (x[rt][ct][r] - mu) * inv * gamma[col] + beta[col];
            }
        }
}

// ---------------------------------------------------------------------------
extern "C" void kernel_launch(void* const* d_in, const int* in_sizes, int n_in,
                              void* d_out, int out_size, void* d_ws, size_t ws_size,
                              hipStream_t stream) {
    const float* feat    = (const float*)d_in[0];
    const float* centers = (const float*)d_in[1];
    const float* textg   = (const float*)d_in[2];
    const float* w1      = (const float*)d_in[3];
    const float* b1      = (const float*)d_in[4];
    const float* w2      = (const float*)d_in[5];
    const float* b2      = (const float*)d_in[6];
    const float* wg      = (const float*)d_in[7];
    const float* bg      = (const float*)d_in[8];
    const float* wtb     = (const float*)d_in[9];
    const float* btb     = (const float*)d_in[10];
    const float* we1     = (const float*)d_in[11];
    const float* be1     = (const float*)d_in[12];
    const float* we2     = (const float*)d_in[13];
    const float* be2     = (const float*)d_in[14];
    const float* wm      = (const float*)d_in[15];
    const float* bm      = (const float*)d_in[16];
    const float* wo      = (const float*)d_in[17];
    const float* bo      = (const float*)d_in[18];
    const float* gamma   = (const float*)d_in[19];
    const float* beta    = (const float*)d_in[20];

    char* ws = (char*)d_ws;
    size_t off = 0;
    int* knn     = (int*)(ws + off);   off += (size_t)BB * NPT * KNN * 4;   // 1 MB
    float* gate  = (float*)(ws + off); off += (size_t)BB * H * 4;           // 64 KB
    float* tbias = (float*)(ws + off); off += (size_t)BB * H * 4;           // 64 KB
    u16* MSGB    = (u16*)(ws + off);   off += (size_t)BB * NPT * H * 2;     // 8 MB
    u16* ctxB    = (u16*)(ws + off);   off += (size_t)BB * NPT * H * 2;     // 8 MB
    u16* featB   = (u16*)(ws + off);   off += (size_t)BB * NPT * H * 2;     // 8 MB
    u16* w2t     = (u16*)(ws + off);   off += (size_t)256 * 256 * 2;        // 128 KB
    u16* we1t    = (u16*)(ws + off);   off += (size_t)128 * 256 * 2;        // 64 KB
    u16* wmt     = (u16*)(ws + off);   off += (size_t)256 * 256 * 2;        // 128 KB
    u16* wot     = (u16*)(ws + off);   off += (size_t)256 * 512 * 2;        // 256 KB
    u16* w1t     = (u16*)(ws + off);   off += (size_t)256 * 32 * 2;         // 16 KB

    prep_kernel<<<5280, 256, 0, stream>>>(feat, w2, we1, wm, wo, w1, b1,
                                          w2t, we1t, wmt, wot, w1t, featB);
    knn_kernel<<<256, 256, 0, stream>>>(centers, knn);
    gate_kernel<<<BB, 512, 0, stream>>>(textg, wg, bg, wtb, btb, gate, tbias);
    msg_mfma<<<BB * NPT / 64, 256, 0, stream>>>(featB, wmt, bm, MSGB);
    edge_mfma<<<BB * NPT / 4, 256, 0, stream>>>(feat, featB, centers, w1t, w2t, b2,
                                                we1t, be1, we2, be2, knn, gate, tbias,
                                                MSGB, ctxB);
    out_mfma<<<BB * NPT / 32, 256, 0, stream>>>(feat, featB, ctxB, wot, bo,
                                                gamma, beta, (float*)d_out);
}

// Round 12
// 345.558 us; speedup vs baseline: 1.2381x; 1.2381x over previous
//
#include <hip/hip_runtime.h>
#include <hip/hip_bf16.h>

#define H 256
#define KNN 16
#define NPT 256
#define BB 64

typedef unsigned short u16;
typedef unsigned int u32;
typedef __attribute__((ext_vector_type(8))) short shortx8;
typedef __attribute__((ext_vector_type(4))) float floatx4;

// RNE f32->bf16 via hw cvt; same rounding as manual (u + 0x7fff + lsb) >> 16.
__device__ __forceinline__ u16 f2b(float f) {
    return __builtin_bit_cast(u16, __float2bfloat16(f));
}
__device__ __forceinline__ float b2f(u16 u) {
    return __uint_as_float(((u32)u) << 16);
}

// tanh via hw exp2: 1 - 2/(exp2(x*2log2e)+1). |err| ~1e-6, saturates correctly.
__device__ __forceinline__ float fast_tanh(float x) {
    float e = __builtin_amdgcn_exp2f(x * 2.88539008177793f);
    return 1.0f - 2.0f * __builtin_amdgcn_rcpf(e + 1.0f);
}

// ---------------------------------------------------------------------------
// K0: prep — bf16 transposed weights [n][k] for MFMA B-fragments only.
// (featB production moved into msg_mfma, which streams those values anyway —
// the standalone 4096-block conversion pass cost ~15-25 us of latency-bound
// grid rounds.) w1t is 256x32: K padded 4->32, k=4 holds b1, k>4 zero.
// NOTE: keep prep/knn/gate SEPARATE dispatches (R9: front restructuring
// pushed the harness poison-writeback drain into edge's window, +42 us).
// NOTE: no register prefetch of gathers in edge (R11: compiler spills >~16
// live floats to scratch, VGPR stays 64, +75 us).
// ---------------------------------------------------------------------------
__global__ __launch_bounds__(256) void prep_kernel(
    const float* __restrict__ w2, const float* __restrict__ we1,
    const float* __restrict__ wm, const float* __restrict__ wo,
    const float* __restrict__ w1, const float* __restrict__ b1,
    u16* __restrict__ w2t, u16* __restrict__ we1t,
    u16* __restrict__ wmt, u16* __restrict__ wot, u16* __restrict__ w1t) {
    int tid = blockIdx.x * 256 + threadIdx.x;
    if (tid < 65536) {                       // w2t: 256 x 256
        int n = tid >> 8, k = tid & 255;
        w2t[tid] = f2b(w2[k * 256 + n]);
    } else if (tid < 98304) {                // we1t: 128 x 256
        int t = tid - 65536;
        int n = t >> 8, k = t & 255;
        we1t[t] = f2b(we1[k * 128 + n]);
    } else if (tid < 163840) {               // wmt: 256 x 256
        int t = tid - 98304;
        int n = t >> 8, k = t & 255;
        wmt[t] = f2b(wm[k * 256 + n]);
    } else if (tid < 294912) {               // wot: 256 x 512
        int t = tid - 163840;
        int n = t >> 9, k = t & 511;
        wot[t] = f2b(wo[k * 256 + n]);
    } else {                                 // w1t: 256 x 32
        int t = tid - 294912;
        int n = t >> 5, k = t & 31;
        float v = (k < 4) ? w1[k * 256 + n] : (k == 4 ? b1[n] : 0.0f);
        w1t[t] = f2b(v);
    }
}

// ---------------------------------------------------------------------------
// K1: exact KNN k=16, stable (d, idx)-lexicographic == jax.lax.top_k(-dist).
// 256 blocks: block = (batch, quarter of points). 4 scanner-waves per point
// group; wave s scans m in [s*64, s*64+64); wave 0 merges.
// ---------------------------------------------------------------------------
__global__ __launch_bounds__(256) void knn_kernel(const float* __restrict__ centers,
                                                  int* __restrict__ knn) {
    __shared__ float cx[NPT], cy[NPT], cz[NPT], sq[NPT];
    __shared__ float dl[4][64][17];
    __shared__ int il[4][64][17];
    int blk = blockIdx.x;
    int b = blk >> 2, n0 = (blk & 3) * 64;
    int h = threadIdx.x;
    int s = h >> 6, pt = h & 63;
    {
        const float* cb = centers + (size_t)b * NPT * 3;
        float x = cb[h * 3 + 0], y = cb[h * 3 + 1], z = cb[h * 3 + 2];
        cx[h] = x; cy[h] = y; cz[h] = z;
        sq[h] = x * x + y * y + z * z;
    }
    __syncthreads();
    int n = n0 + pt;
    float x = cx[n], y = cy[n], z = cz[n], sn = sq[n];
    float bd[KNN];
    int bi[KNN];
#pragma unroll
    for (int j = 0; j < KNN; j++) { bd[j] = 1e30f; bi[j] = 0x7fffffff; }
    for (int mm = 0; mm < 64; mm++) {
        int m = s * 64 + mm;
        float dot = x * cx[m] + y * cy[m] + z * cz[m];
        float d2 = (sn + sq[m]) - 2.0f * dot;
        float d = sqrtf(fmaxf(d2, 0.0f));
        if (d < bd[KNN - 1]) {  // in-order scan + strict < == lexicographic
            bd[KNN - 1] = d; bi[KNN - 1] = m;
#pragma unroll
            for (int p = KNN - 1; p > 0; --p) {
                if (bd[p - 1] > bd[p]) {
                    float td = bd[p - 1]; bd[p - 1] = bd[p]; bd[p] = td;
                    int ti = bi[p - 1]; bi[p - 1] = bi[p]; bi[p] = ti;
                }
            }
        }
    }
#pragma unroll
    for (int j = 0; j < KNN; j++) { dl[s][pt][j] = bd[j]; il[s][pt][j] = bi[j]; }
    __syncthreads();
    if (s == 0) {
        float md[KNN];
        int mi[KNN];
#pragma unroll
        for (int j = 0; j < KNN; j++) { md[j] = dl[0][pt][j]; mi[j] = il[0][pt][j]; }
        for (int t = 1; t < 4; t++) {
            for (int j = 0; j < KNN; j++) {
                float d = dl[t][pt][j];
                int idx = il[t][pt][j];
                bool ins = (d < md[KNN - 1]) || (d == md[KNN - 1] && idx < mi[KNN - 1]);
                if (!ins) break;  // source list sorted lexicographically
                md[KNN - 1] = d; mi[KNN - 1] = idx;
#pragma unroll
                for (int p = KNN - 1; p > 0; --p) {
                    bool sw = (md[p - 1] > md[p]) ||
                              (md[p - 1] == md[p] && mi[p - 1] > mi[p]);
                    if (sw) {
                        float td = md[p - 1]; md[p - 1] = md[p]; md[p] = td;
                        int ti = mi[p - 1]; mi[p - 1] = mi[p]; mi[p] = ti;
                    }
                }
            }
        }
        int* kp = knn + (b * NPT + n0 + pt) * KNN;
#pragma unroll
        for (int j = 0; j < KNN; j++) kp[j] = mi[j];
    }
}

// ---------------------------------------------------------------------------
// K2: text gate / bias per batch. 512 threads: 0..255 gate, 256..511 tbias.
// ---------------------------------------------------------------------------
__global__ __launch_bounds__(512) void gate_kernel(const float* __restrict__ tg_g,
                                                   const float* __restrict__ wg,
                                                   const float* __restrict__ bg,
                                                   const float* __restrict__ wtb,
                                                   const float* __restrict__ btb,
                                                   float* __restrict__ gate,
                                                   float* __restrict__ tbias) {
    __shared__ float tg[H];
    int b = blockIdx.x, t = threadIdx.x;
    if (t < H) tg[t] = tg_g[b * H + t];
    __syncthreads();
    int h = t & 255;
    if (t < H) {
        float ag = bg[h];
#pragma unroll 4
        for (int i = 0; i < H; i++) ag += tg[i] * wg[i * H + h];
        gate[b * H + h] = 1.0f / (1.0f + expf(-ag));
    } else {
        float ab = btb[h];
#pragma unroll 4
        for (int i = 0; i < H; i++) ab += tg[i] * wtb[i * H + h];
        tbias[b * H + h] = ab;
    }
}

// ---------------------------------------------------------------------------
// K3: MSGB = bf16(relu(feat @ Wm + bm)), MFMA, 64 points/block.
// Reads feat f32 and emits featB (bf16 copy) as a side-product of the LDS
// staging it already does — replaces prep's standalone featB pass.
// ---------------------------------------------------------------------------
__global__ __launch_bounds__(256, 4) void msg_mfma(const float* __restrict__ feat,
                                                   const u16* __restrict__ wmt,
                                                   const float* __restrict__ bm,
                                                   u16* __restrict__ MSGB,
                                                   u16* __restrict__ featB) {
    __shared__ __attribute__((aligned(16))) u16 A[64][264];
    int p0 = blockIdx.x * 64, h = threadIdx.x;
    int w = h >> 6, lane = h & 63, quad = lane >> 4, lq = lane & 15;
#pragma unroll 8
    for (int row = 0; row < 64; row++) {
        u16 v = f2b(feat[(size_t)(p0 + row) * H + h]);
        A[row][h] = v;
        featB[(size_t)(p0 + row) * H + h] = v;
    }
    __syncthreads();
    floatx4 acc[4][4];
#pragma unroll
    for (int rt = 0; rt < 4; rt++)
#pragma unroll
        for (int ct = 0; ct < 4; ct++) acc[rt][ct] = (floatx4){0, 0, 0, 0};
#pragma unroll 2
    for (int kt = 0; kt < 8; kt++) {
        shortx8 bf[4];
#pragma unroll
        for (int ct = 0; ct < 4; ct++)
            bf[ct] = *(const shortx8*)&wmt[(w * 64 + ct * 16 + lq) * 256 + kt * 32 + quad * 8];
#pragma unroll
        for (int rt = 0; rt < 4; rt++) {
            shortx8 a = *(const shortx8*)&A[rt * 16 + lq][kt * 32 + quad * 8];
#pragma unroll
            for (int ct = 0; ct < 4; ct++)
                acc[rt][ct] = __builtin_amdgcn_mfma_f32_16x16x32_bf16(a, bf[ct], acc[rt][ct], 0, 0, 0);
        }
    }
#pragma unroll
    for (int ct = 0; ct < 4; ct++) {
        int col = w * 64 + ct * 16 + lq;
        float bmc = bm[col];
#pragma unroll
        for (int rt = 0; rt < 4; rt++)
#pragma unroll
            for (int r = 0; r < 4; r++) {
                int row = rt * 16 + quad * 4 + r;
                MSGB[(size_t)(p0 + row) * H + col] = f2b(fmaxf(acc[rt][ct][r] + bmc, 0.0f));
            }
    }
}

// ---------------------------------------------------------------------------
// K4: fused edge pipeline, 4 points/block (M=64 edges). g1 via MFMA with
// bias folded into K-slot 4. fb/MSG gathers + ctx write in bf16.
// Exact R10 version (143 us proven; R11's register prefetch spilled).
// ---------------------------------------------------------------------------
__global__ __launch_bounds__(256, 4) void edge_mfma(
    const float* __restrict__ feat, const u16* __restrict__ featB,
    const float* __restrict__ centers,
    const u16* __restrict__ w1t,
    const u16* __restrict__ w2t, const float* __restrict__ b2v,
    const u16* __restrict__ we1t, const float* __restrict__ be1,
    const float* __restrict__ we2, const float* __restrict__ be2,
    const int* __restrict__ knn, const float* __restrict__ gateG,
    const float* __restrict__ tbiasG, const u16* __restrict__ MSGB,
    u16* __restrict__ ctxB) {
    __shared__ __attribute__((aligned(16))) u16 A[64][264];  // g1 then edge_feat
    __shared__ float fnS[4][H];
    __shared__ __attribute__((aligned(16))) float geomS[64][4];
    __shared__ int nidxS[64];
    __shared__ float part[4][64];
    __shared__ float logitsS[64];
    __shared__ float alphaS[64];

    int bn0 = blockIdx.x * 4;
    int b = bn0 >> 8, n0 = bn0 & 255;
    int h = threadIdx.x;
    int w = h >> 6, lane = h & 63, quad = lane >> 4, lq = lane & 15;

    // phase 0: nidx + fn staging
    if (h < 64) nidxS[h] = knn[bn0 * KNN + h];
#pragma unroll
    for (int p = 0; p < 4; p++)
        fnS[p][h] = feat[(size_t)(bn0 + p) * H + h];
    // phase 1: geom per edge-row (h<64: point p=h>>4, neighbor j=h&15);
    // reads only own-thread nidxS[h] write from phase 0.
    if (h < 64) {
        int p = h >> 4;
        int m = nidxS[h];
        int n = n0 + p;
        const float* cb = centers + (size_t)b * NPT * 3;
        float rx = cb[m * 3 + 0] - cb[n * 3 + 0];
        float ry = cb[m * 3 + 1] - cb[n * 3 + 1];
        float rz = cb[m * 3 + 2] - cb[n * 3 + 2];
        float dist = sqrtf(rx * rx + ry * ry + rz * rz) + 1e-6f;
        geomS[h][0] = rx; geomS[h][1] = ry; geomS[h][2] = rz;
        geomS[h][3] = log1pf(dist);
    }
    __syncthreads();

    // phase 2: g1[64][256] = relu(geomP @ W1t) via MFMA (K=32 padded, k=4 bias)
    {
        shortx8 bw1[4];
#pragma unroll
        for (int ct = 0; ct < 4; ct++)
            bw1[ct] = *(const shortx8*)&w1t[(w * 64 + ct * 16 + lq) * 32 + quad * 8];
#pragma unroll
        for (int rt = 0; rt < 4; rt++) {
            shortx8 ag = {0, 0, 0, 0, 0, 0, 0, 0};
            if (quad == 0) {
                float4 g = *(const float4*)&geomS[rt * 16 + lq][0];
                ag[0] = (short)f2b(g.x);
                ag[1] = (short)f2b(g.y);
                ag[2] = (short)f2b(g.z);
                ag[3] = (short)f2b(g.w);
                ag[4] = (short)0x3F80;  // 1.0 -> multiplies bias row of w1t
            }
#pragma unroll
            for (int ct = 0; ct < 4; ct++) {
                floatx4 accg = __builtin_amdgcn_mfma_f32_16x16x32_bf16(
                    ag, bw1[ct], (floatx4){0, 0, 0, 0}, 0, 0, 0);
#pragma unroll
                for (int r = 0; r < 4; r++)
                    A[rt * 16 + quad * 4 + r][w * 64 + ct * 16 + lq] =
                        f2b(fmaxf(accg[r], 0.0f));
            }
        }
    }
    __syncthreads();

    // GEMM1: C1[64][256] = g1 @ W2
    floatx4 acc[4][4];
#pragma unroll
    for (int rt = 0; rt < 4; rt++)
#pragma unroll
        for (int ct = 0; ct < 4; ct++) acc[rt][ct] = (floatx4){0, 0, 0, 0};
#pragma unroll 2
    for (int kt = 0; kt < 8; kt++) {
        shortx8 bf[4];
#pragma unroll
        for (int ct = 0; ct < 4; ct++)
            bf[ct] = *(const shortx8*)&w2t[(w * 64 + ct * 16 + lq) * 256 + kt * 32 + quad * 8];
#pragma unroll
        for (int rt = 0; rt < 4; rt++) {
            shortx8 a = *(const shortx8*)&A[rt * 16 + lq][kt * 32 + quad * 8];
#pragma unroll
            for (int ct = 0; ct < 4; ct++)
                acc[rt][ct] = __builtin_amdgcn_mfma_f32_16x16x32_bf16(a, bf[ct], acc[rt][ct], 0, 0, 0);
        }
    }
    __syncthreads();  // all g1 reads done

    // epilogue1: edge_feat = tanh(fn + fnb + relu(C1+b2)*gate + tbias) -> A
#pragma unroll
    for (int ct = 0; ct < 4; ct++) {
        int col = w * 64 + ct * 16 + lq;
        float b2c = b2v[col];
        float gc = gateG[b * H + col];
        float tc = tbiasG[b * H + col];
#pragma unroll
        for (int rt = 0; rt < 4; rt++) {
            float fnc = fnS[rt][col];
#pragma unroll
            for (int r = 0; r < 4; r++) {
                int row = rt * 16 + quad * 4 + r;
                float fb = b2f(featB[((size_t)b * NPT + nidxS[row]) * H + col]);
                float emb = fmaxf(acc[rt][ct][r] + b2c, 0.0f);
                float ef = fast_tanh(fnc + fb + emb * gc + tc);
                A[row][col] = f2b(ef);
            }
        }
    }
    __syncthreads();

    // GEMM2: C2[64][128] = edge_feat @ We1
    floatx4 acc2[4][2];
#pragma unroll
    for (int rt = 0; rt < 4; rt++)
#pragma unroll
        for (int c2 = 0; c2 < 2; c2++) acc2[rt][c2] = (floatx4){0, 0, 0, 0};
#pragma unroll 2
    for (int kt = 0; kt < 8; kt++) {
        shortx8 bf[2];
#pragma unroll
        for (int c2 = 0; c2 < 2; c2++)
            bf[c2] = *(const shortx8*)&we1t[(w * 32 + c2 * 16 + lq) * 256 + kt * 32 + quad * 8];
#pragma unroll
        for (int rt = 0; rt < 4; rt++) {
            shortx8 a = *(const shortx8*)&A[rt * 16 + lq][kt * 32 + quad * 8];
#pragma unroll
            for (int c2 = 0; c2 < 2; c2++)
                acc2[rt][c2] = __builtin_amdgcn_mfma_f32_16x16x32_bf16(a, bf[c2], acc2[rt][c2], 0, 0, 0);
        }
    }

    // logits partials
    float pl[4][4];
#pragma unroll
    for (int rt = 0; rt < 4; rt++)
#pragma unroll
        for (int r = 0; r < 4; r++) pl[rt][r] = 0.0f;
#pragma unroll
    for (int c2 = 0; c2 < 2; c2++) {
        int col = w * 32 + c2 * 16 + lq;
        float be1c = be1[col], w2c = we2[col];
#pragma unroll
        for (int rt = 0; rt < 4; rt++)
#pragma unroll
            for (int r = 0; r < 4; r++)
                pl[rt][r] += fmaxf(acc2[rt][c2][r] + be1c, 0.0f) * w2c;
    }
#pragma unroll
    for (int d = 1; d < 16; d <<= 1)
#pragma unroll
        for (int rt = 0; rt < 4; rt++)
#pragma unroll
            for (int r = 0; r < 4; r++) pl[rt][r] += __shfl_xor(pl[rt][r], d, 16);
    if (lq == 0) {
#pragma unroll
        for (int rt = 0; rt < 4; rt++)
#pragma unroll
            for (int r = 0; r < 4; r++)
                part[w][rt * 16 + quad * 4 + r] = pl[rt][r];
    }
    __syncthreads();
    if (h < 64)
        logitsS[h] = part[0][h] + part[1][h] + part[2][h] + part[3][h] + be2[0];
    __syncthreads();
    if (h < 64) {
        int base = (h >> 4) * 16;
        float mx = -1e30f;
#pragma unroll
        for (int j = 0; j < KNN; j++) mx = fmaxf(mx, logitsS[base + j]);
        float sum = 0.0f;
#pragma unroll
        for (int j = 0; j < KNN; j++) sum += expf(logitsS[base + j] - mx);
        alphaS[h] = expf(logitsS[h] - mx) / sum;
    }
    __syncthreads();

    // ctx: thread -> (point p, 4 cols); bf16 gather over 16 nbrs, bf16 write
    {
        int p = h >> 6, cg = (h & 63) * 4;
        float4 c = {0, 0, 0, 0};
#pragma unroll
        for (int j = 0; j < KNN; j++) {
            float al = alphaS[p * 16 + j];
            const u32* mp = (const u32*)&MSGB[((size_t)b * NPT + nidxS[p * 16 + j]) * H + cg];
            u32 m0 = mp[0], m1 = mp[1];
            c.x += al * __uint_as_float(m0 << 16);
            c.y += al * __uint_as_float(m0 & 0xFFFF0000u);
            c.z += al * __uint_as_float(m1 << 16);
            c.w += al * __uint_as_float(m1 & 0xFFFF0000u);
        }
        uint2 st;
        st.x = (u32)f2b(c.x) | ((u32)f2b(c.y) << 16);
        st.y = (u32)f2b(c.z) | ((u32)f2b(c.w) << 16);
        *(uint2*)&ctxB[(size_t)(bn0 + p) * H + cg] = st;
    }
}

// ---------------------------------------------------------------------------
// K5: out = LN(feat + relu([feat|ctx] @ Wo + bo)), MFMA, 32 points/block.
// ---------------------------------------------------------------------------
__global__ __launch_bounds__(256, 4) void out_mfma(const float* __restrict__ feat,
                                                   const u16* __restrict__ featB,
                                                   const u16* __restrict__ ctxB,
                                                   const u16* __restrict__ wot,
                                                   const float* __restrict__ bo,
                                                   const float* __restrict__ gamma,
                                                   const float* __restrict__ beta,
                                                   float* __restrict__ out) {
    __shared__ __attribute__((aligned(16))) u16 A[32][520];
    __shared__ float redS[4][32], redS2[4][32];
    int p0 = blockIdx.x * 32, h = threadIdx.x;
    int w = h >> 6, lane = h & 63, quad = lane >> 4, lq = lane & 15;
#pragma unroll 8
    for (int row = 0; row < 32; row++) {
        A[row][h]       = featB[(size_t)(p0 + row) * H + h];
        A[row][256 + h] = ctxB[(size_t)(p0 + row) * H + h];
    }
    __syncthreads();
    floatx4 acc[2][4];
#pragma unroll
    for (int rt = 0; rt < 2; rt++)
#pragma unroll
        for (int ct = 0; ct < 4; ct++) acc[rt][ct] = (floatx4){0, 0, 0, 0};
#pragma unroll 2
    for (int kt = 0; kt < 16; kt++) {
        shortx8 bf[4];
#pragma unroll
        for (int ct = 0; ct < 4; ct++)
            bf[ct] = *(const shortx8*)&wot[(w * 64 + ct * 16 + lq) * 512 + kt * 32 + quad * 8];
#pragma unroll
        for (int rt = 0; rt < 2; rt++) {
            shortx8 a = *(const shortx8*)&A[rt * 16 + lq][kt * 32 + quad * 8];
#pragma unroll
            for (int ct = 0; ct < 4; ct++)
                acc[rt][ct] = __builtin_amdgcn_mfma_f32_16x16x32_bf16(a, bf[ct], acc[rt][ct], 0, 0, 0);
        }
    }
    float x[2][4][4];
    float sm[2][4], sq2[2][4];
#pragma unroll
    for (int rt = 0; rt < 2; rt++)
#pragma unroll
        for (int r = 0; r < 4; r++) { sm[rt][r] = 0.0f; sq2[rt][r] = 0.0f; }
#pragma unroll
    for (int rt = 0; rt < 2; rt++)
#pragma unroll
        for (int ct = 0; ct < 4; ct++) {
            int col = w * 64 + ct * 16 + lq;
            float boc = bo[col];
#pragma unroll
            for (int r = 0; r < 4; r++) {
                int row = rt * 16 + quad * 4 + r;
                float xx = feat[(size_t)(p0 + row) * H + col] +
                           fmaxf(acc[rt][ct][r] + boc, 0.0f);
                x[rt][ct][r] = xx;
                sm[rt][r] += xx;
                sq2[rt][r] += xx * xx;
            }
        }
#pragma unroll
    for (int d = 1; d < 16; d <<= 1)
#pragma unroll
        for (int rt = 0; rt < 2; rt++)
#pragma unroll
            for (int r = 0; r < 4; r++) {
                sm[rt][r] += __shfl_xor(sm[rt][r], d, 16);
                sq2[rt][r] += __shfl_xor(sq2[rt][r], d, 16);
            }
    if (lq == 0) {
#pragma unroll
        for (int rt = 0; rt < 2; rt++)
#pragma unroll
            for (int r = 0; r < 4; r++) {
                redS[w][rt * 16 + quad * 4 + r] = sm[rt][r];
                redS2[w][rt * 16 + quad * 4 + r] = sq2[rt][r];
            }
    }
    __syncthreads();
#pragma unroll
    for (int rt = 0; rt < 2; rt++)
#pragma unroll
        for (int r = 0; r < 4; r++) {
            int row = rt * 16 + quad * 4 + r;
            float s1 = redS[0][row] + redS[1][row] + redS[2][row] + redS[3][row];
            float s2 = redS2[0][row] + redS2[1][row] + redS2[2][row] + redS2[3][row];
            float mu = s1 * (1.0f / H);
            float var = s2 * (1.0f / H) - mu * mu;
            float inv = rsqrtf(fmaxf(var, 0.0f) + 1e-5f);
#pragma unroll
            for (int ct = 0; ct < 4; ct++) {
                int col = w * 64 + ct * 16 + lq;
                out[(size_t)(p0 + row) * H + col] =
                    (x[rt][ct][r] - mu) * inv * gamma[col] + beta[col];
            }
        }
}

// ---------------------------------------------------------------------------
extern "C" void kernel_launch(void* const* d_in, const int* in_sizes, int n_in,
                              void* d_out, int out_size, void* d_ws, size_t ws_size,
                              hipStream_t stream) {
    const float* feat    = (const float*)d_in[0];
    const float* centers = (const float*)d_in[1];
    const float* textg   = (const float*)d_in[2];
    const float* w1      = (const float*)d_in[3];
    const float* b1      = (const float*)d_in[4];
    const float* w2      = (const float*)d_in[5];
    const float* b2      = (const float*)d_in[6];
    const float* wg      = (const float*)d_in[7];
    const float* bg      = (const float*)d_in[8];
    const float* wtb     = (const float*)d_in[9];
    const float* btb     = (const float*)d_in[10];
    const float* we1     = (const float*)d_in[11];
    const float* be1     = (const float*)d_in[12];
    const float* we2     = (const float*)d_in[13];
    const float* be2     = (const float*)d_in[14];
    const float* wm      = (const float*)d_in[15];
    const float* bm      = (const float*)d_in[16];
    const float* wo      = (const float*)d_in[17];
    const float* bo      = (const float*)d_in[18];
    const float* gamma   = (const float*)d_in[19];
    const float* beta    = (const float*)d_in[20];

    char* ws = (char*)d_ws;
    size_t off = 0;
    int* knn     = (int*)(ws + off);   off += (size_t)BB * NPT * KNN * 4;   // 1 MB
    float* gate  = (float*)(ws + off); off += (size_t)BB * H * 4;           // 64 KB
    float* tbias = (float*)(ws + off); off += (size_t)BB * H * 4;           // 64 KB
    u16* MSGB    = (u16*)(ws + off);   off += (size_t)BB * NPT * H * 2;     // 8 MB
    u16* ctxB    = (u16*)(ws + off);   off += (size_t)BB * NPT * H * 2;     // 8 MB
    u16* featB   = (u16*)(ws + off);   off += (size_t)BB * NPT * H * 2;     // 8 MB
    u16* w2t     = (u16*)(ws + off);   off += (size_t)256 * 256 * 2;        // 128 KB
    u16* we1t    = (u16*)(ws + off);   off += (size_t)128 * 256 * 2;        // 64 KB
    u16* wmt     = (u16*)(ws + off);   off += (size_t)256 * 256 * 2;        // 128 KB
    u16* wot     = (u16*)(ws + off);   off += (size_t)256 * 512 * 2;        // 256 KB
    u16* w1t     = (u16*)(ws + off);   off += (size_t)256 * 32 * 2;         // 16 KB

    prep_kernel<<<1184, 256, 0, stream>>>(w2, we1, wm, wo, w1, b1,
                                          w2t, we1t, wmt, wot, w1t);
    knn_kernel<<<256, 256, 0, stream>>>(centers, knn);
    gate_kernel<<<BB, 512, 0, stream>>>(textg, wg, bg, wtb, btb, gate, tbias);
    msg_mfma<<<BB * NPT / 64, 256, 0, stream>>>(feat, wmt, bm, MSGB, featB);
    edge_mfma<<<BB * NPT / 4, 256, 0, stream>>>(feat, featB, centers, w1t, w2t, b2,
                                                we1t, be1, we2, be2, knn, gate, tbias,
                                                MSGB, ctxB);
    out_mfma<<<BB * NPT / 32, 256, 0, stream>>>(feat, featB, ctxB, wot, bo,
                                                gamma, beta, (float*)d_out);
}